// Round 10
// baseline (374.039 us; speedup 1.0000x reference)
//
#include <hip/hip_runtime.h>

typedef unsigned short u16;
typedef __attribute__((ext_vector_type(8))) short bf16x8;   // 8 x bf16 (4 VGPRs)
typedef __attribute__((ext_vector_type(4))) float f32x4;

#define NLEV 5
#define CCH 256
#define KTOT 2304            // 9 taps * 256 ci
#define P_TOT 8525           // sum HW
#define PP_TOT 9165          // sum (H+2)*(W+2)
#define PLS (PP_TOT*64)      // activation plane stride (u16), 4 planes of 64 ci
#define HSTR 11776           // halo LDS plane stride (u16) = 23 slabs * 512

__constant__ int   c_HW[NLEV]     = {6400, 1600, 400, 100, 25};
__constant__ int   c_W[NLEV]      = {80, 40, 20, 10, 5};    // H == W (square)
__constant__ int   c_off[NLEV]    = {0, 6400, 8000, 8400, 8500};
__constant__ int   c_poff[NLEV]   = {0, 6724, 8488, 8972, 9116};
__constant__ int   c_tls[NLEV+1]  = {0, 50, 65, 71, 73, 74};  // 16x8 tile starts
__constant__ int   c_ntx[NLEV]    = {5, 3, 2, 1, 1};          // tiles across
__constant__ float c_stridef[NLEV]= {8.f, 16.f, 32.f, 64.f, 128.f};

__device__ __forceinline__ u16 f2bf(float f){
  union { float f; unsigned u; } v; v.f = f;
  unsigned r = v.u + 0x7fffu + ((v.u >> 16) & 1u);   // RNE
  return (u16)(r >> 16);
}

// async global->LDS: 64 lanes x 16B; HW writes lane i to ldsbase + i*16.
// GLOBAL address is per-lane arbitrary; only the LDS dest is lane-ordered.
__device__ __forceinline__ void g2l16(const u16* g, u16* l, int lane){
#if defined(__has_builtin)
#if __has_builtin(__builtin_amdgcn_global_load_lds)
  __builtin_amdgcn_global_load_lds(
      (const __attribute__((address_space(1))) unsigned int*)g,
      (__attribute__((address_space(3))) unsigned int*)l, 16, 0, 0);
  return;
#endif
#endif
  *(uint4*)(l + lane*8) = *(const uint4*)g;  // fallback: sync copy
}

// s_waitcnt imm (gfx9: vm[3:0]+[15:14], exp[6:4], lgkm[11:8])
#define WAIT_VM8   0x0F78   // vmcnt(8): my previous A-batch done, next in flight
#define WAIT_VM0   0x0F70   // vmcnt(0)
#define WAIT_LGKM0 0xC07F   // lgkmcnt(0)

// ---------------------------------------------------------------------------
// Barrier-free-K halo implicit-GEMM conv 3x3.
// Prologue: stage ALL 4 ci-planes of the 18x10 halo into LDS (92 KB,
// read-only afterwards) + wave-private A stage 0; ONE __syncthreads; then the
// K-loop has NO block barriers: each wave stages its own 64co x 64k A slab
// (8 KB dbuf, per-wave vmcnt(8) distance waits) -> 4 independent staging
// chains per CU (R5-measured ~2.4x ingest of one block-wide chain).
// K order cc-major: t = cc*9+tap; A k-stage = tap*4+cc (pack unchanged).
// MODE 0: towers, BM=256 (wave = 64co x 128px, acc[4][8]), grid (74,1,2);
//         GN stats fused (all 32 groups/block). 148 blocks = single round.
// MODE 1: heads, BM=128 (wave = (wv&1) co-half x (wv>>1) px-half), grid
//         (74,1,2): br0 score (m<80), br1 pred+iou (m<5) -> out[n][85].
// LDS total 160,000 B -> 1 block/CU (intentional: tail-free 148-block grid).
// ---------------------------------------------------------------------------
template<int MODE>
__global__ __launch_bounds__(256, 1) void gemm_conv(
    const u16* __restrict__ Xc, const u16* __restrict__ Xb,
    const u16* __restrict__ Wc, const u16* __restrict__ Wb,
    const float* __restrict__ bc, const float* __restrict__ bb,
    float* __restrict__ Yc, float* __restrict__ Yb,
    float* __restrict__ stats,
    const float* __restrict__ predb, const float* __restrict__ ioub,
    const float* __restrict__ scales, float* __restrict__ out)
{
  constexpr int NT = (MODE == 0) ? 8 : 4;      // n-frags per wave
  __shared__ u16 hB[4*HSTR];                   // 94208 B: 4 planes, padded
  __shared__ u16 sA[4][2][4096];               // 65536 B: per-wave A dbuf
  __shared__ float sstat[32][2];

  const int ptile = blockIdx.x, br = blockIdx.z;
  int lv = 0;
  #pragma unroll
  for (int i = 1; i < NLEV; i++) if (ptile >= c_tls[i]) lv = i;
  const int tidx = ptile - c_tls[lv];
  const int ntx = c_ntx[lv];
  const int ty0 = (tidx / ntx) * 8, tx0 = (tidx - (tidx / ntx) * ntx) * 16;
  const int W = c_W[lv], wrow2 = W + 2;

  const int tid = threadIdx.x, wv = tid >> 6, ln = tid & 63;
  const int quad = ln >> 4, l15 = ln & 15;

  const u16* __restrict__ X  = br ? Xb : Xc;   // planar activations
  const u16* __restrict__ WA = br ? Wb : Wc;   // packed weights

  const int ASTR = (MODE == 0) ? 16384 : 8192; // per-stage A u16s
  const u16* abase = WA + (size_t)(((MODE == 0) ? wv : (wv & 1)) * 8) * 512 + ln*8;

  // Halo per-lane source pointers (per wave: slabs j = wv+4i, j<23).
  const u16* hptr[6]; int hnum = 0;
  #pragma unroll
  for (int i = 0; i < 6; i++) {
    const int j = wv + 4*i;
    if (j < 23) {
      const int item = j*64 + ln;
      int hp = item >> 3; if (hp >= 180) hp -= 180;
      const int g = item & 7;
      const int hy = hp / 18, hx = hp - hy*18;
      const int prow = c_poff[lv] + (ty0 + hy)*wrow2 + tx0 + hx;
      hptr[i] = X + (size_t)prow*64 + ((g ^ (hp & 7)) << 3);
      hnum = i + 1;
    }
  }

  auto stageA = [&](int s, int b) {           // s = k-stage index (tap*4+cc)
    const u16* as = abase + (size_t)s * ASTR;
    u16* da = &sA[wv][b][0];
    #pragma unroll
    for (int j = 0; j < 8; j++) g2l16(as + j*512, da + j*512, ln);
  };

  f32x4 acc[4][NT];
  #pragma unroll
  for (int i = 0; i < 4; i++)
    #pragma unroll
    for (int j = 0; j < NT; j++) acc[i][j] = (f32x4){0.f, 0.f, 0.f, 0.f};

  if (MODE == 0 && tid < 64) sstat[tid >> 1][tid & 1] = 0.f;

  // ---- prologue: full halo (all 4 planes) + A stage 0; one barrier ----
  for (int i = 0; i < hnum; i++) {
    const int j = wv + 4*i;
    #pragma unroll
    for (int cc = 0; cc < 4; cc++)
      g2l16(hptr[i] + (size_t)cc*PLS, hB + cc*HSTR + j*512, ln);
  }
  stageA(0, 0);                                // sidx(0) = 0
  __syncthreads();                             // halo visible to all; vm drained
  stageA(4, 1);                                // sidx(1): t=1 -> tap1,cc0 -> 4

  // ---- barrier-free K-loop: t = cc*9 + tap ----
  #pragma unroll 1
  for (int t = 0; t < 36; t++) {
    if (t < 35) __builtin_amdgcn_s_waitcnt(WAIT_VM8);   // my A(t) landed
    else        __builtin_amdgcn_s_waitcnt(WAIT_VM0);
    const int cc = t / 9, tap = t - cc*9;
    const int dh = tap / 3, dw = tap - dh*3;
    const u16* myA = &sA[wv][t & 1][0];
    const u16* hpl = &hB[cc * HSTR];
    bf16x8 af[2][4], bf[2][NT];
    #pragma unroll
    for (int sub = 0; sub < 2; sub++) {
      const int q = sub*4 + quad;
      const int swzA = (q ^ (l15 & 7)) * 8;
      #pragma unroll
      for (int mt = 0; mt < 4; mt++)
        af[sub][mt] = *(const bf16x8*)&myA[(mt*16 + l15)*64 + swzA];
      #pragma unroll
      for (int nt = 0; nt < NT; nt++) {
        const int py = (MODE == 0) ? nt : ((wv >> 1)*4 + nt);
        const int hp = (py + dh)*18 + l15 + dw;
        bf[sub][nt] = *(const bf16x8*)&hpl[hp*64 + ((q ^ (hp & 7)) << 3)];
      }
    }
    __builtin_amdgcn_s_waitcnt(WAIT_LGKM0);    // frags in VGPRs; buf reusable
    if (t + 2 < 36) {
      const int t2 = t + 2, cc2 = t2 / 9, tap2 = t2 - cc2*9;
      stageA(tap2*4 + cc2, t & 1);
    }
    #pragma unroll
    for (int sub = 0; sub < 2; sub++)
      #pragma unroll
      for (int mt = 0; mt < 4; mt++)
        #pragma unroll
        for (int nt = 0; nt < NT; nt++)
          acc[mt][nt] = __builtin_amdgcn_mfma_f32_16x16x32_bf16(
              af[sub][mt], bf[sub][nt], acc[mt][nt], 0, 0, 0);
  }

  const int gx = tx0 + l15;
  if (MODE == 0) {
    const float* __restrict__ bias = br ? bb : bc;
    float* __restrict__ Y = br ? Yb : Yc;
    #pragma unroll
    for (int mt = 0; mt < 4; mt++) {
      const int mrow = wv*64 + mt*16 + quad*4;
      const f32x4 bv = *(const f32x4*)&bias[mrow];
      float s = 0.f, sq = 0.f;
      #pragma unroll
      for (int nt = 0; nt < NT; nt++) {
        const int gy = ty0 + nt;
        f32x4 v = acc[mt][nt] + bv;
        if (gy < W && gx < W) {
          const size_t n = (size_t)(c_off[lv] + gy*W + gx);
          *(f32x4*)&Y[n*CCH + mrow] = v;
          #pragma unroll
          for (int r = 0; r < 4; r++) { s += v[r]; sq += v[r]*v[r]; }
        }
      }
      #pragma unroll
      for (int o = 1; o < 16; o <<= 1) { s += __shfl_xor(s, o); sq += __shfl_xor(sq, o); }
      if (l15 == 0) {
        const int g = mrow >> 3;               // GN group 0..31
        atomicAdd(&sstat[g][0], s);
        atomicAdd(&sstat[g][1], sq);
      }
    }
    __syncthreads();
    if (tid < 64) {
      const int g = tid >> 1, c = tid & 1;
      atomicAdd(&stats[((br*NLEV + lv)*32 + g)*2 + c], sstat[g][c]);
    }
  } else {
    const float scl = scales[lv];
    const float stf = c_stridef[lv];
    #pragma unroll
    for (int mt = 0; mt < 4; mt++) {
      const int mr0 = (wv & 1)*64 + mt*16 + quad*4;
      if (mr0 >= 85) continue;
      #pragma unroll
      for (int nt = 0; nt < NT; nt++) {
        const int gy = ty0 + (wv >> 1)*4 + nt;
        if (gy >= W || gx >= W) continue;
        const size_t n = (size_t)(c_off[lv] + gy*W + gx);
        const f32x4 v = acc[mt][nt];
        #pragma unroll
        for (int r = 0; r < 4; r++) {
          const int m = mr0 + r;
          if (br == 0) {
            if (m < 80) out[n*85 + m] = v[r] + bc[m];          // logits
          } else {
            if (m < 4) {
              const float t = (v[r] + predb[m]) * scl;         // Scale module
              out[n*85 + 80 + m] = fmaxf(t, 0.f) * stf;        // relu * stride
            } else if (m == 4) {
              out[n*85 + 84] = v[r] + ioub[0];                 // iou
            }
          }
        }
      }
    }
  }
}

// GN finalize + affine + ReLU + bf16 cast into PLANAR padded layout.
// Y already includes conv bias.
__global__ __launch_bounds__(256) void gn_relu(
    const float* __restrict__ Yc, const float* __restrict__ Yb,
    const float* __restrict__ stats,
    const float* __restrict__ gwc, const float* __restrict__ gbc,
    const float* __restrict__ gwb, const float* __restrict__ gbb,
    u16* __restrict__ Xc, u16* __restrict__ Xb)
{
  const int t = blockIdx.x * 256 + threadIdx.x;
  if (t >= 2 * P_TOT * 32) return;
  const int br = t / (P_TOT * 32);
  const int r  = t - br * (P_TOT * 32);
  const int pg = r >> 5;
  const int c0 = (r & 31) << 3;
  int lv = 0;
  #pragma unroll
  for (int i = 1; i < NLEV; i++) if (pg >= c_off[i]) lv = i;
  const int pl = pg - c_off[lv];
  const int Wl = c_W[lv];
  const int g = c0 >> 3;
  const float* st = &stats[(((size_t)br*NLEV + lv)*32 + g)*2];
  const float cnt = 8.f * (float)c_HW[lv];
  const float mean = st[0] / cnt;
  const float var  = st[1] / cnt - mean*mean;
  const float rstd = rsqrtf(var + 1e-5f);
  const float* Y  = br ? Yb : Yc;
  const float* gw = br ? gwb : gwc;
  const float* gb = br ? gbb : gbc;
  u16* X = br ? Xb : Xc;
  const float* y = &Y[(size_t)pg*CCH + c0];
  const int h = pl / Wl, wi = pl - h*Wl;
  const size_t pidx = (size_t)(c_poff[lv] + (h+1)*(Wl+2) + (wi+1));
  union { u16 u[8]; uint4 v; } pk;
  #pragma unroll
  for (int i = 0; i < 8; i++) {
    const float v = (y[i] - mean)*rstd*gw[c0+i] + gb[c0+i];
    pk.u[i] = f2bf(fmaxf(v, 0.f));
  }
  *(uint4*)&X[(size_t)(c0 >> 6)*PLS + pidx*64 + (c0 & 63)] = pk.v;
}

// fp32 NCHW feats -> bf16 planar padded
__global__ __launch_bounds__(256) void feat2bf(
    const float* __restrict__ p3, const float* __restrict__ p4,
    const float* __restrict__ p5, const float* __restrict__ p6,
    const float* __restrict__ p7, u16* __restrict__ X)
{
  const int t = blockIdx.x * 256 + threadIdx.x;
  if (t >= P_TOT * 32) return;
  const int pg = t >> 5, c0 = (t & 31) << 3;
  int lv = 0;
  #pragma unroll
  for (int i = 1; i < NLEV; i++) if (pg >= c_off[i]) lv = i;
  const int pl = pg - c_off[lv];
  const float* src = lv==0 ? p3 : lv==1 ? p4 : lv==2 ? p5 : lv==3 ? p6 : p7;
  const int HW = c_HW[lv], Wl = c_W[lv];
  const int h = pl / Wl, wi = pl - h*Wl;
  const size_t pidx = (size_t)(c_poff[lv] + (h+1)*(Wl+2) + (wi+1));
  union { u16 u[8]; uint4 v; } pk;
  #pragma unroll
  for (int i = 0; i < 8; i++)
    pk.u[i] = f2bf(src[(size_t)(c0+i)*HW + pl]);
  *(uint4*)&X[(size_t)(c0 >> 6)*PLS + pidx*64 + (c0 & 63)] = pk.v;
}

// tower weights [l][co][ci][9] fp32 -> PACKED stage-major swizzled bf16:
// dst = l*589824 + ((s*32 + (co>>3))*64 + (co&7)*8 + ((kl>>3)^(co&7)))*8 + (kl&7)
// where k = tap*256+ci, s = k>>6 = tap*4 + (ci>>6), kl = k&63.
__global__ __launch_bounds__(256) void wconv(
    const float* __restrict__ cw, const float* __restrict__ bw,
    u16* __restrict__ Wc, u16* __restrict__ Wb)
{
  const size_t N = (size_t)4*256*KTOT;
  const size_t t = (size_t)blockIdx.x * 256 + threadIdx.x;
  if (t >= 2*N) return;
  const float* src = (t < N) ? cw : bw;
  u16* dst = (t < N) ? Wc : Wb;
  const size_t i = (t < N) ? t : t - N;
  const size_t lc = i / KTOT;
  const int kk = (int)(i - lc*KTOT);
  const int l = (int)(lc >> 8), co = (int)(lc & 255);
  const int tap = kk >> 8, ci = kk & 255;
  const int s = kk >> 6, kl = kk & 63;
  const int r = co & 7, p = (kl >> 3) ^ r;
  const size_t d = (size_t)l*589824 +
      ((size_t)((s*32 + (co >> 3))*64 + r*8 + p))*8 + (kl & 7);
  dst[d] = f2bf(src[(lc*256 + ci)*9 + tap]);
}

// head weights -> packed 128-row swizzled (cls: 80 rows; box: 4 pred + 1 iou)
__global__ __launch_bounds__(256) void hconv(
    const float* __restrict__ sw, const float* __restrict__ pw,
    const float* __restrict__ iw, u16* __restrict__ Whc, u16* __restrict__ Whb)
{
  const int N = 128 * KTOT;
  const int t = blockIdx.x * 256 + threadIdx.x;
  if (t >= 2*N) return;
  const int i = (t < N) ? t : t - N;
  const int co = i / KTOT, kk = i - co*KTOT;
  const int tap = kk >> 8, ci = kk & 255;
  const int s = kk >> 6, kl = kk & 63;
  const int r = co & 7, p = (kl >> 3) ^ r;
  const size_t d = ((size_t)((s*16 + (co >> 3))*64 + r*8 + p))*8 + (kl & 7);
  float v = 0.f;
  if (t < N) {
    if (co < 80) v = sw[(co*256 + ci)*9 + tap];
    Whc[d] = f2bf(v);
  } else {
    if (co < 4)       v = pw[(co*256 + ci)*9 + tap];
    else if (co == 4) v = iw[ci*9 + tap];
    Whb[d] = f2bf(v);
  }
}

extern "C" void kernel_launch(void* const* d_in, const int* in_sizes, int n_in,
                              void* d_out, int out_size, void* d_ws, size_t ws_size,
                              hipStream_t stream)
{
  const float* p3      = (const float*)d_in[0];
  const float* p4      = (const float*)d_in[1];
  const float* p5      = (const float*)d_in[2];
  const float* p6      = (const float*)d_in[3];
  const float* p7      = (const float*)d_in[4];
  const float* cls_w   = (const float*)d_in[5];
  const float* cls_b   = (const float*)d_in[6];
  const float* cls_gw  = (const float*)d_in[7];
  const float* cls_gb  = (const float*)d_in[8];
  const float* box_w   = (const float*)d_in[9];
  const float* box_b   = (const float*)d_in[10];
  const float* box_gw  = (const float*)d_in[11];
  const float* box_gb  = (const float*)d_in[12];
  const float* score_w = (const float*)d_in[13];
  const float* score_b = (const float*)d_in[14];
  const float* pred_w  = (const float*)d_in[15];
  const float* pred_b  = (const float*)d_in[16];
  const float* iou_w   = (const float*)d_in[17];
  const float* iou_b   = (const float*)d_in[18];
  const float* scales  = (const float*)d_in[19];
  float* out = (float*)d_out;

  char* w = (char*)d_ws;
  size_t o = 0;
  auto alloc = [&](size_t b) { void* p = w + o; o += (b + 255) & ~(size_t)255; return p; };
  // X buffers + stats first: zeroed by ONE memset (all 256B multiples)
  u16*   XF = (u16*)alloc((size_t)PP_TOT*CCH*2);   // planar [4][PP_TOT][64]
  u16*   XC = (u16*)alloc((size_t)PP_TOT*CCH*2);
  u16*   XB = (u16*)alloc((size_t)PP_TOT*CCH*2);
  float* ST = (float*)alloc((size_t)4*2*NLEV*32*2*4);   // [layer][br][lv][32][2]
  u16*  WRC = (u16*)alloc((size_t)4*256*KTOT*2);
  u16*  WRB = (u16*)alloc((size_t)4*256*KTOT*2);
  u16*  WHC = (u16*)alloc((size_t)128*KTOT*2);
  u16*  WHB = (u16*)alloc((size_t)128*KTOT*2);
  float* YC = (float*)alloc((size_t)P_TOT*CCH*4);
  float* YB = (float*)alloc((size_t)P_TOT*CCH*4);

  // zero padded activation borders + all layers' GN stats in one shot
  hipMemsetAsync(XF, 0, (size_t)3*PP_TOT*CCH*2 + (size_t)4*2*NLEV*32*2*4, stream);

  wconv<<<dim3((unsigned)(((size_t)2*4*256*KTOT + 255)/256)), 256, 0, stream>>>(cls_w, box_w, WRC, WRB);
  hconv<<<dim3((2*128*KTOT + 255)/256), 256, 0, stream>>>(score_w, pred_w, iou_w, WHC, WHB);
  feat2bf<<<dim3((P_TOT*32 + 255)/256), 256, 0, stream>>>(p3, p4, p5, p6, p7, XF);

  const u16* xci = XF; const u16* xbi = XF;
  for (int l = 0; l < 4; l++) {
    float* STl = ST + (size_t)l*2*NLEV*32*2;
    gemm_conv<0><<<dim3(74, 1, 2), 256, 0, stream>>>(
        xci, xbi, WRC + (size_t)l*589824, WRB + (size_t)l*589824,
        cls_b + l*256, box_b + l*256, YC, YB, STl,
        nullptr, nullptr, nullptr, nullptr);
    gn_relu<<<dim3((2*P_TOT*32 + 255)/256), 256, 0, stream>>>(
        YC, YB, STl, cls_gw + l*256, cls_gb + l*256, box_gw + l*256, box_gb + l*256,
        XC, XB);
    xci = XC; xbi = XB;
  }
  gemm_conv<1><<<dim3(74, 1, 2), 256, 0, stream>>>(
      xci, xbi, WHC, WHB, score_b, nullptr, nullptr, nullptr, nullptr,
      pred_b, iou_b, scales, out);
}

// Round 11
// 354.755 us; speedup vs baseline: 1.0544x; 1.0544x over previous
//
#include <hip/hip_runtime.h>

typedef unsigned short u16;
typedef __attribute__((ext_vector_type(8))) short bf16x8;   // 8 x bf16 (4 VGPRs)
typedef __attribute__((ext_vector_type(4))) float f32x4;

#define NLEV 5
#define CCH 256
#define KTOT 2304            // 9 taps * 256 ci
#define P_TOT 8525           // sum HW
#define PP_TOT 9165          // sum (H+2)*(W+2)
#define PLS (PP_TOT*64)      // activation plane stride (u16), 4 planes of 64 ci
#define HSTR 11776           // halo LDS plane stride (u16) = 23 slabs * 512

__constant__ int   c_HW[NLEV]     = {6400, 1600, 400, 100, 25};
__constant__ int   c_W[NLEV]      = {80, 40, 20, 10, 5};    // H == W (square)
__constant__ int   c_off[NLEV]    = {0, 6400, 8000, 8400, 8500};
__constant__ int   c_poff[NLEV]   = {0, 6724, 8488, 8972, 9116};
__constant__ int   c_tls[NLEV+1]  = {0, 50, 65, 71, 73, 74};  // 16x8 tile starts
__constant__ int   c_ntx[NLEV]    = {5, 3, 2, 1, 1};          // tiles across
__constant__ float c_stridef[NLEV]= {8.f, 16.f, 32.f, 64.f, 128.f};

__device__ __forceinline__ u16 f2bf(float f){
  union { float f; unsigned u; } v; v.f = f;
  unsigned r = v.u + 0x7fffu + ((v.u >> 16) & 1u);   // RNE
  return (u16)(r >> 16);
}

// async global->LDS: 64 lanes x 16B; HW writes lane i to ldsbase + i*16.
__device__ __forceinline__ void g2l16(const u16* g, u16* l, int lane){
#if defined(__has_builtin)
#if __has_builtin(__builtin_amdgcn_global_load_lds)
  __builtin_amdgcn_global_load_lds(
      (const __attribute__((address_space(1))) unsigned int*)g,
      (__attribute__((address_space(3))) unsigned int*)l, 16, 0, 0);
  return;
#endif
#endif
  *(uint4*)(l + lane*8) = *(const uint4*)g;  // fallback: sync copy
}

// s_waitcnt imm (gfx9: vm[3:0] bits3:0, vm[5:4] bits15:14, exp[6:4], lgkm[11:8])
#define WAIT_VM4   0x0F74   // vmcnt(4):  A(t) landed, A(t+1) in flight
#define WAIT_VM10  0x0F7A   // vmcnt(10): A(t) landed; halo batch(6)+A(t+1) fly
#define WAIT_VM0   0x0F70   // vmcnt(0)
#define WAIT_LGKM0 0xC07F   // lgkmcnt(0)

// ---------------------------------------------------------------------------
// Wave-chain halo implicit-GEMM conv 3x3, 2 blocks/CU (LDS 80,000 B).
// BM=128 (blockIdx.y = mtile): each wave owns 32 co; A staged wave-private
// (4 slabs/stage, 8 KB dbuf/wave) with per-wave distance-2 vmcnt waits
// (R10-measured ~1.85x per chain). Halo (18x10 px, 64ci planes) kept as a
// 2-plane LDS double-buffer; K is cc-major (t = cc*9 + tap); plane cc+1 is
// prefetched at the cc boundary with 9 stages of slack. Only 3 block
// barriers in the K-loop (t=9,18,27), each preceded by per-wave vmcnt that
// (by in-order retirement) proves the halo batch landed.
// vmcnt schedule: t==10||t==19 -> vmcnt(10); t==35 -> vmcnt(0); else vmcnt(4).
// MODE 0: towers, grid (74,2,2); GN stats fused in epilogue.
// MODE 1: heads,  grid (74,1,2): br0 score (m<80), br1 pred+iou (m<5).
// ---------------------------------------------------------------------------
template<int MODE>
__global__ __launch_bounds__(256, 2) void gemm_conv(
    const u16* __restrict__ Xc, const u16* __restrict__ Xb,
    const u16* __restrict__ Wc, const u16* __restrict__ Wb,
    const float* __restrict__ bc, const float* __restrict__ bb,
    float* __restrict__ Yc, float* __restrict__ Yb,
    float* __restrict__ stats,
    const float* __restrict__ predb, const float* __restrict__ ioub,
    const float* __restrict__ scales, float* __restrict__ out)
{
  __shared__ u16 hB[2*HSTR];        // 47104 B: halo plane dbuf (slot = cc&1)
  __shared__ u16 sA[4][2][2048];    // 32768 B: per-wave A dbuf (4 slabs each)
  __shared__ float sstat[16][2];    // 128 B

  const int ptile = blockIdx.x;
  const int mtile = (MODE == 0) ? blockIdx.y : 0;
  const int br = blockIdx.z;
  int lv = 0;
  #pragma unroll
  for (int i = 1; i < NLEV; i++) if (ptile >= c_tls[i]) lv = i;
  const int tidx = ptile - c_tls[lv];
  const int ntx = c_ntx[lv];
  const int ty0 = (tidx / ntx) * 8, tx0 = (tidx - (tidx / ntx) * ntx) * 16;
  const int W = c_W[lv], wrow2 = W + 2;

  const int tid = threadIdx.x, wv = tid >> 6, ln = tid & 63;
  const int quad = ln >> 4, l15 = ln & 15;

  const u16* __restrict__ X  = br ? Xb : Xc;   // planar activations
  const u16* __restrict__ WA = br ? Wb : Wc;   // packed weights

  const int ASTR = (MODE == 0) ? 16384 : 8192; // per-stage A u16s
  const u16* abase = WA +
      (size_t)(((MODE == 0) ? mtile*16 : 0) + wv*4) * 512 + ln*8;

  // Halo per-lane source pointers: slab j = wv+4i (j>22 -> idempotent dup of
  // this wave's previous slab so every wave issues exactly 6 loads).
  const u16* hptr[6]; int hslab[6];
  #pragma unroll
  for (int i = 0; i < 6; i++) {
    int j = wv + 4*i;
    if (j > 22) j -= 4;                        // wv3,i=5 -> slab 19 (dup)
    hslab[i] = j;
    const int item = j*64 + ln;
    int hp = item >> 3; if (hp >= 180) hp -= 180;
    const int g = item & 7;
    const int hy = hp / 18, hx = hp - hy*18;
    const int prow = c_poff[lv] + (ty0 + hy)*wrow2 + tx0 + hx;
    hptr[i] = X + (size_t)prow*64 + ((g ^ (hp & 7)) << 3);
  }

  auto stageH = [&](int plane) {               // 6 loads/wave
    u16* dst = &hB[(plane & 1) * HSTR];
    const size_t cof = (size_t)plane * PLS;
    #pragma unroll
    for (int i = 0; i < 6; i++)
      g2l16(hptr[i] + cof, dst + hslab[i]*512, ln);
  };
  auto stageA = [&](int s, int b) {            // 4 loads/wave
    const u16* as = abase + (size_t)s * ASTR;
    u16* da = &sA[wv][b][0];
    #pragma unroll
    for (int j = 0; j < 4; j++) g2l16(as + j*512, da + j*512, ln);
  };

  f32x4 acc[2][8];
  #pragma unroll
  for (int i = 0; i < 2; i++)
    #pragma unroll
    for (int j = 0; j < 8; j++) acc[i][j] = (f32x4){0.f, 0.f, 0.f, 0.f};

  if (MODE == 0 && tid < 32) sstat[tid >> 1][tid & 1] = 0.f;

  // ---- prologue: halo planes 0,1 + A stages for t=0,1; one barrier ----
  stageH(0);
  stageH(1);
  stageA(0, 0);                                // t=0: tap0 cc0 -> s=0
  stageA(4, 1);                                // t=1: tap1 cc0 -> s=4
  __syncthreads();                             // drains vm; LDS visible

  // ---- K-loop: t = cc*9 + tap, wave-private A chains, 3 barriers ----
  int cc = 0, tap = 0;
  #pragma unroll 1
  for (int t = 0; t < 36; t++) {
    if (t == 10 || t == 19) __builtin_amdgcn_s_waitcnt(WAIT_VM10);
    else if (t == 35)       __builtin_amdgcn_s_waitcnt(WAIT_VM0);
    else                    __builtin_amdgcn_s_waitcnt(WAIT_VM4);
    if (tap == 0 && cc > 0) {                  // t = 9,18,27
      __builtin_amdgcn_sched_barrier(0);
      __builtin_amdgcn_s_barrier();            // all waves done w/ plane cc-2
      __builtin_amdgcn_sched_barrier(0);
      if (cc < 3) stageH(cc + 1);              // into slot (cc+1)&1
    }
    const u16* myA = &sA[wv][t & 1][0];
    const u16* hpl = &hB[(cc & 1) * HSTR];
    const int dh = tap / 3, dw = tap - dh*3;
    bf16x8 af[2][2], bf[2][8];
    #pragma unroll
    for (int sub = 0; sub < 2; sub++) {
      const int q = sub*4 + quad;
      const int swzA = (q ^ (l15 & 7)) * 8;
      #pragma unroll
      for (int mt = 0; mt < 2; mt++)
        af[sub][mt] = *(const bf16x8*)&myA[(mt*16 + l15)*64 + swzA];
      #pragma unroll
      for (int nt = 0; nt < 8; nt++) {
        const int hp = (nt + dh)*18 + l15 + dw;
        bf[sub][nt] = *(const bf16x8*)&hpl[hp*64 + ((q ^ (hp & 7)) << 3)];
      }
    }
    __builtin_amdgcn_s_waitcnt(WAIT_LGKM0);    // frags in VGPRs; buf reusable
    if (t < 34) {
      int tap2 = tap + 2, cc2 = cc;
      if (tap2 >= 9) { tap2 -= 9; cc2++; }
      stageA(tap2*4 + cc2, t & 1);             // lands 2 stages from now
    }
    #pragma unroll
    for (int sub = 0; sub < 2; sub++)
      #pragma unroll
      for (int mt = 0; mt < 2; mt++)
        #pragma unroll
        for (int nt = 0; nt < 8; nt++)
          acc[mt][nt] = __builtin_amdgcn_mfma_f32_16x16x32_bf16(
              af[sub][mt], bf[sub][nt], acc[mt][nt], 0, 0, 0);
    if (++tap == 9) { tap = 0; cc++; }
  }

  const int gx = tx0 + l15;
  if (MODE == 0) {
    const float* __restrict__ bias = br ? bb : bc;
    float* __restrict__ Y = br ? Yb : Yc;
    #pragma unroll
    for (int mt = 0; mt < 2; mt++) {
      const int mloc = wv*32 + mt*16 + quad*4;
      const int mrow = mtile*128 + mloc;
      const f32x4 bv = *(const f32x4*)&bias[mrow];
      float s = 0.f, sq = 0.f;
      #pragma unroll
      for (int nt = 0; nt < 8; nt++) {
        const int gy = ty0 + nt;
        f32x4 v = acc[mt][nt] + bv;
        if (gy < W && gx < W) {
          const size_t n = (size_t)(c_off[lv] + gy*W + gx);
          *(f32x4*)&Y[n*CCH + mrow] = v;
          #pragma unroll
          for (int r = 0; r < 4; r++) { s += v[r]; sq += v[r]*v[r]; }
        }
      }
      #pragma unroll
      for (int o = 1; o < 16; o <<= 1) { s += __shfl_xor(s, o); sq += __shfl_xor(sq, o); }
      if (l15 == 0) {
        const int g = mloc >> 3;               // local 8-ch GN group 0..15
        atomicAdd(&sstat[g][0], s);
        atomicAdd(&sstat[g][1], sq);
      }
    }
    __syncthreads();
    if (tid < 32) {
      const int g = tid >> 1, c = tid & 1;
      atomicAdd(&stats[((br*NLEV + lv)*32 + mtile*16 + g)*2 + c], sstat[g][c]);
    }
  } else {
    const float scl = scales[lv];
    const float stf = c_stridef[lv];
    #pragma unroll
    for (int mt = 0; mt < 2; mt++) {
      const int mr0 = wv*32 + mt*16 + quad*4;
      if (mr0 >= 85) continue;
      #pragma unroll
      for (int nt = 0; nt < 8; nt++) {
        const int gy = ty0 + nt;
        if (gy >= W || gx >= W) continue;
        const size_t n = (size_t)(c_off[lv] + gy*W + gx);
        const f32x4 v = acc[mt][nt];
        #pragma unroll
        for (int r = 0; r < 4; r++) {
          const int m = mr0 + r;
          if (br == 0) {
            if (m < 80) out[n*85 + m] = v[r] + bc[m];          // logits
          } else {
            if (m < 4) {
              const float t = (v[r] + predb[m]) * scl;         // Scale module
              out[n*85 + 80 + m] = fmaxf(t, 0.f) * stf;        // relu * stride
            } else if (m == 4) {
              out[n*85 + 84] = v[r] + ioub[0];                 // iou
            }
          }
        }
      }
    }
  }
}

// GN finalize + affine + ReLU + bf16 cast into PLANAR padded layout.
// Y already includes conv bias.
__global__ __launch_bounds__(256) void gn_relu(
    const float* __restrict__ Yc, const float* __restrict__ Yb,
    const float* __restrict__ stats,
    const float* __restrict__ gwc, const float* __restrict__ gbc,
    const float* __restrict__ gwb, const float* __restrict__ gbb,
    u16* __restrict__ Xc, u16* __restrict__ Xb)
{
  const int t = blockIdx.x * 256 + threadIdx.x;
  if (t >= 2 * P_TOT * 32) return;
  const int br = t / (P_TOT * 32);
  const int r  = t - br * (P_TOT * 32);
  const int pg = r >> 5;
  const int c0 = (r & 31) << 3;
  int lv = 0;
  #pragma unroll
  for (int i = 1; i < NLEV; i++) if (pg >= c_off[i]) lv = i;
  const int pl = pg - c_off[lv];
  const int Wl = c_W[lv];
  const int g = c0 >> 3;
  const float* st = &stats[(((size_t)br*NLEV + lv)*32 + g)*2];
  const float cnt = 8.f * (float)c_HW[lv];
  const float mean = st[0] / cnt;
  const float var  = st[1] / cnt - mean*mean;
  const float rstd = rsqrtf(var + 1e-5f);
  const float* Y  = br ? Yb : Yc;
  const float* gw = br ? gwb : gwc;
  const float* gb = br ? gbb : gbc;
  u16* X = br ? Xb : Xc;
  const float* y = &Y[(size_t)pg*CCH + c0];
  const int h = pl / Wl, wi = pl - h*Wl;
  const size_t pidx = (size_t)(c_poff[lv] + (h+1)*(Wl+2) + (wi+1));
  union { u16 u[8]; uint4 v; } pk;
  #pragma unroll
  for (int i = 0; i < 8; i++) {
    const float v = (y[i] - mean)*rstd*gw[c0+i] + gb[c0+i];
    pk.u[i] = f2bf(fmaxf(v, 0.f));
  }
  *(uint4*)&X[(size_t)(c0 >> 6)*PLS + pidx*64 + (c0 & 63)] = pk.v;
}

// fp32 NCHW feats -> bf16 planar padded
__global__ __launch_bounds__(256) void feat2bf(
    const float* __restrict__ p3, const float* __restrict__ p4,
    const float* __restrict__ p5, const float* __restrict__ p6,
    const float* __restrict__ p7, u16* __restrict__ X)
{
  const int t = blockIdx.x * 256 + threadIdx.x;
  if (t >= P_TOT * 32) return;
  const int pg = t >> 5, c0 = (t & 31) << 3;
  int lv = 0;
  #pragma unroll
  for (int i = 1; i < NLEV; i++) if (pg >= c_off[i]) lv = i;
  const int pl = pg - c_off[lv];
  const float* src = lv==0 ? p3 : lv==1 ? p4 : lv==2 ? p5 : lv==3 ? p6 : p7;
  const int HW = c_HW[lv], Wl = c_W[lv];
  const int h = pl / Wl, wi = pl - h*Wl;
  const size_t pidx = (size_t)(c_poff[lv] + (h+1)*(Wl+2) + (wi+1));
  union { u16 u[8]; uint4 v; } pk;
  #pragma unroll
  for (int i = 0; i < 8; i++)
    pk.u[i] = f2bf(src[(size_t)(c0+i)*HW + pl]);
  *(uint4*)&X[(size_t)(c0 >> 6)*PLS + pidx*64 + (c0 & 63)] = pk.v;
}

// tower weights [l][co][ci][9] fp32 -> PACKED stage-major swizzled bf16:
// dst = l*589824 + ((s*32 + (co>>3))*64 + (co&7)*8 + ((kl>>3)^(co&7)))*8 + (kl&7)
// where k = tap*256+ci, s = k>>6 = tap*4 + (ci>>6), kl = k&63.
__global__ __launch_bounds__(256) void wconv(
    const float* __restrict__ cw, const float* __restrict__ bw,
    u16* __restrict__ Wc, u16* __restrict__ Wb)
{
  const size_t N = (size_t)4*256*KTOT;
  const size_t t = (size_t)blockIdx.x * 256 + threadIdx.x;
  if (t >= 2*N) return;
  const float* src = (t < N) ? cw : bw;
  u16* dst = (t < N) ? Wc : Wb;
  const size_t i = (t < N) ? t : t - N;
  const size_t lc = i / KTOT;
  const int kk = (int)(i - lc*KTOT);
  const int l = (int)(lc >> 8), co = (int)(lc & 255);
  const int tap = kk >> 8, ci = kk & 255;
  const int s = kk >> 6, kl = kk & 63;
  const int r = co & 7, p = (kl >> 3) ^ r;
  const size_t d = (size_t)l*589824 +
      ((size_t)((s*32 + (co >> 3))*64 + r*8 + p))*8 + (kl & 7);
  dst[d] = f2bf(src[(lc*256 + ci)*9 + tap]);
}

// head weights -> packed 128-row swizzled (cls: 80 rows; box: 4 pred + 1 iou)
__global__ __launch_bounds__(256) void hconv(
    const float* __restrict__ sw, const float* __restrict__ pw,
    const float* __restrict__ iw, u16* __restrict__ Whc, u16* __restrict__ Whb)
{
  const int N = 128 * KTOT;
  const int t = blockIdx.x * 256 + threadIdx.x;
  if (t >= 2*N) return;
  const int i = (t < N) ? t : t - N;
  const int co = i / KTOT, kk = i - co*KTOT;
  const int tap = kk >> 8, ci = kk & 255;
  const int s = kk >> 6, kl = kk & 63;
  const int r = co & 7, p = (kl >> 3) ^ r;
  const size_t d = ((size_t)((s*16 + (co >> 3))*64 + r*8 + p))*8 + (kl & 7);
  float v = 0.f;
  if (t < N) {
    if (co < 80) v = sw[(co*256 + ci)*9 + tap];
    Whc[d] = f2bf(v);
  } else {
    if (co < 4)       v = pw[(co*256 + ci)*9 + tap];
    else if (co == 4) v = iw[ci*9 + tap];
    Whb[d] = f2bf(v);
  }
}

extern "C" void kernel_launch(void* const* d_in, const int* in_sizes, int n_in,
                              void* d_out, int out_size, void* d_ws, size_t ws_size,
                              hipStream_t stream)
{
  const float* p3      = (const float*)d_in[0];
  const float* p4      = (const float*)d_in[1];
  const float* p5      = (const float*)d_in[2];
  const float* p6      = (const float*)d_in[3];
  const float* p7      = (const float*)d_in[4];
  const float* cls_w   = (const float*)d_in[5];
  const float* cls_b   = (const float*)d_in[6];
  const float* cls_gw  = (const float*)d_in[7];
  const float* cls_gb  = (const float*)d_in[8];
  const float* box_w   = (const float*)d_in[9];
  const float* box_b   = (const float*)d_in[10];
  const float* box_gw  = (const float*)d_in[11];
  const float* box_gb  = (const float*)d_in[12];
  const float* score_w = (const float*)d_in[13];
  const float* score_b = (const float*)d_in[14];
  const float* pred_w  = (const float*)d_in[15];
  const float* pred_b  = (const float*)d_in[16];
  const float* iou_w   = (const float*)d_in[17];
  const float* iou_b   = (const float*)d_in[18];
  const float* scales  = (const float*)d_in[19];
  float* out = (float*)d_out;

  char* w = (char*)d_ws;
  size_t o = 0;
  auto alloc = [&](size_t b) { void* p = w + o; o += (b + 255) & ~(size_t)255; return p; };
  // X buffers + stats first: zeroed by ONE memset (all 256B multiples)
  u16*   XF = (u16*)alloc((size_t)PP_TOT*CCH*2);   // planar [4][PP_TOT][64]
  u16*   XC = (u16*)alloc((size_t)PP_TOT*CCH*2);
  u16*   XB = (u16*)alloc((size_t)PP_TOT*CCH*2);
  float* ST = (float*)alloc((size_t)4*2*NLEV*32*2*4);   // [layer][br][lv][32][2]
  u16*  WRC = (u16*)alloc((size_t)4*256*KTOT*2);
  u16*  WRB = (u16*)alloc((size_t)4*256*KTOT*2);
  u16*  WHC = (u16*)alloc((size_t)128*KTOT*2);
  u16*  WHB = (u16*)alloc((size_t)128*KTOT*2);
  float* YC = (float*)alloc((size_t)P_TOT*CCH*4);
  float* YB = (float*)alloc((size_t)P_TOT*CCH*4);

  // zero padded activation borders + all layers' GN stats in one shot
  hipMemsetAsync(XF, 0, (size_t)3*PP_TOT*CCH*2 + (size_t)4*2*NLEV*32*2*4, stream);

  wconv<<<dim3((unsigned)(((size_t)2*4*256*KTOT + 255)/256)), 256, 0, stream>>>(cls_w, box_w, WRC, WRB);
  hconv<<<dim3((2*128*KTOT + 255)/256), 256, 0, stream>>>(score_w, pred_w, iou_w, WHC, WHB);
  feat2bf<<<dim3((P_TOT*32 + 255)/256), 256, 0, stream>>>(p3, p4, p5, p6, p7, XF);

  const u16* xci = XF; const u16* xbi = XF;
  for (int l = 0; l < 4; l++) {
    float* STl = ST + (size_t)l*2*NLEV*32*2;
    gemm_conv<0><<<dim3(74, 2, 2), 256, 0, stream>>>(
        xci, xbi, WRC + (size_t)l*589824, WRB + (size_t)l*589824,
        cls_b + l*256, box_b + l*256, YC, YB, STl,
        nullptr, nullptr, nullptr, nullptr);
    gn_relu<<<dim3((2*P_TOT*32 + 255)/256), 256, 0, stream>>>(
        YC, YB, STl, cls_gw + l*256, cls_gb + l*256, box_gw + l*256, box_gb + l*256,
        XC, XB);
    xci = XC; xbi = XB;
  }
  gemm_conv<1><<<dim3(74, 1, 2), 256, 0, stream>>>(
      xci, xbi, WHC, WHB, score_b, nullptr, nullptr, nullptr, nullptr,
      pred_b, iou_b, scales, out);
}